// Round 10
// baseline (459.546 us; speedup 1.0000x reference)
//
#include <hip/hip_runtime.h>

#define N_NODES  50000
#define N_EDGES  1600000
#define DIM      128
#define N_GRAPHS 512
#define SCAN_BLOCK 1024
#define NB1   196        // coarse buckets = ceil(50000/256)
#define B1    256        // phase-1 blocks
#define CHUNK 6250       // edges per phase-1 block (256*6250 = 1.6M exactly)
#define BH_N  (NB1 * B1) // 50176
#define BH_BLK ((BH_N + SCAN_BLOCK - 1) / SCAN_BLOCK)  // 49
#define XS_BLOCKS 6250   // xsplit: 50000*128/4 / 256
#define WS_BLOCKS 384    // wsplit: 6*16384 / 256
#define GB_BLOCKS 196    // graph_bounds: ceil(50000/256)

typedef unsigned int uint_t;
typedef unsigned short ushort_t;
typedef __attribute__((ext_vector_type(8))) short bf16x8;
typedef __attribute__((ext_vector_type(4))) float f32x4;

__device__ inline uint_t bf_rne(float f) {   // fp32 -> bf16 bits, round-nearest-even
    uint_t u = __float_as_uint(f);
    return (u + 0x7fffu + ((u >> 16) & 1u)) >> 16;
}

// split f into hi (bf16) and lo (bf16 of residual); f ~= hi + lo to ~2^-17 rel
__device__ inline void bf_split(float f, uint_t& h, uint_t& l) {
    h = bf_rne(f);
    float hf = __uint_as_float(h << 16);
    l = bf_rne(f - hf);
}

// ---------------------------------------------------------------------------
// Combined: p1_count (CSR bucket histogram) + xsplit + wsplit + graph_bounds,
// partitioned by blockIdx range. All parts only read kernel inputs.
// ---------------------------------------------------------------------------
__global__ __launch_bounds__(256) void prep_kernel(
        const int* __restrict__ dst, int* __restrict__ bh,
        const float* __restrict__ x, ushort_t* __restrict__ xh, ushort_t* __restrict__ xl,
        const float* w0, const float* w1, const float* w2,
        const float* w3, const float* w4, const float* w5,
        ushort_t* __restrict__ whi,
        const int* __restrict__ batch, int* __restrict__ gstart) {
    __shared__ int hist[NB1];
    int b = blockIdx.x, t = threadIdx.x;
    if (b < B1) {
        // --- p1_count: coarse histogram (dst>>8) for this edge chunk ---
        for (int i = t; i < NB1; i += 256) hist[i] = 0;
        __syncthreads();
        int base = b * CHUNK;
        for (int i = t; i < CHUNK; i += 256)
            atomicAdd(&hist[dst[base + i] >> 8], 1);
        __syncthreads();
        for (int i = t; i < NB1; i += 256) bh[i * B1 + b] = hist[i];
    } else if (b < B1 + XS_BLOCKS) {
        int i = (b - B1) * 256 + t;                 // exactly 1.6M float4 groups
        float4 v = ((const float4*)x)[i];
        uint_t h0,h1,h2,h3,l0,l1,l2,l3;
        bf_split(v.x,h0,l0); bf_split(v.y,h1,l1); bf_split(v.z,h2,l2); bf_split(v.w,h3,l3);
        uint2 ho; ho.x = h0 | (h1 << 16); ho.y = h2 | (h3 << 16);
        uint2 lo; lo.x = l0 | (l1 << 16); lo.y = l2 | (l3 << 16);
        ((uint2*)xh)[i] = ho;
        ((uint2*)xl)[i] = lo;
    } else if (b < B1 + XS_BLOCKS + WS_BLOCKS) {
        int i = (b - B1 - XS_BLOCKS) * 256 + t;     // exactly 6*16384
        int ws = i >> 14, off = i & 16383;
        const float* w = (ws == 0) ? w0 : (ws == 1) ? w1 : (ws == 2) ? w2
                       : (ws == 3) ? w3 : (ws == 4) ? w4 : w5;
        whi[i] = (ushort_t)bf_rne(w[off]);
    } else {
        int i = (b - B1 - XS_BLOCKS - WS_BLOCKS) * 256 + t;
        if (i < N_NODES) {
            int bb = batch[i];
            int prev = (i == 0) ? -1 : batch[i - 1];
            for (int g = prev + 1; g <= bb; g++) gstart[g] = i;
            if (i == 0) {
                int last = batch[N_NODES - 1];
                for (int g = last + 1; g <= N_GRAPHS; g++) gstart[g] = N_NODES;
            }
        }
    }
}

// hierarchical exclusive scan over bh (BH_N entries)
__global__ void block_reduce_n(const int* __restrict__ in, int* __restrict__ bsum, int n) {
    __shared__ int red[256];
    int b = blockIdx.x, t = threadIdx.x;
    int base = b * SCAN_BLOCK;
    int s = 0;
    for (int i = t; i < SCAN_BLOCK; i += 256) {
        int idx = base + i;
        s += (idx < n) ? in[idx] : 0;
    }
    red[t] = s; __syncthreads();
    for (int off = 128; off; off >>= 1) {
        if (t < off) red[t] += red[t + off];
        __syncthreads();
    }
    if (t == 0) bsum[b] = red[0];
}

__global__ void scan_tops_n(const int* __restrict__ bsum, int* __restrict__ bofs, int nblk) {
    if (threadIdx.x == 0) {
        int acc = 0;
        for (int i = 0; i < nblk; i++) { bofs[i] = acc; acc += bsum[i]; }
    }
}

__global__ void block_scan_n(const int* __restrict__ in, const int* __restrict__ bofs,
                             int* __restrict__ ofs, int n) {
    __shared__ int tmp[SCAN_BLOCK];
    int b = blockIdx.x, t = threadIdx.x;
    int i = b * SCAN_BLOCK + t;
    tmp[t] = (i < n) ? in[i] : 0;
    __syncthreads();
    for (int off = 1; off < SCAN_BLOCK; off <<= 1) {
        int add = (t >= off) ? tmp[t - off] : 0;
        __syncthreads();
        tmp[t] += add;
        __syncthreads();
    }
    if (i < n) ofs[i + 1] = tmp[t] + bofs[b];
    if (i == 0) ofs[0] = 0;
}

__global__ __launch_bounds__(256) void p1_scatter(const int* __restrict__ src,
                                                  const int* __restrict__ dst,
                                                  const int* __restrict__ bhofs,
                                                  uint_t* __restrict__ ebuf1) {
    __shared__ int cur[NB1];
    int b = blockIdx.x, t = threadIdx.x;
    for (int i = t; i < NB1; i += 256) cur[i] = bhofs[i * B1 + b];
    __syncthreads();
    int base = b * CHUNK;
    for (int i = t; i < CHUNK; i += 256) {
        int d = dst[base + i];
        int pos = atomicAdd(&cur[d >> 8], 1);
        ebuf1[pos] = (uint_t)src[base + i] | ((uint_t)(d & 255) << 16);
    }
}

// one block per coarse bucket: hist over low byte -> row_start + final scatter.
__global__ __launch_bounds__(256) void p2_sort(const uint_t* __restrict__ ebuf1,
                                               const int* __restrict__ bhofs,
                                               int* __restrict__ row_start,
                                               int* __restrict__ ebuf) {
    __shared__ int hist[256];
    __shared__ int scn[256];
    __shared__ int cur[256];
    int k = blockIdx.x, t = threadIdx.x;
    int s = bhofs[k * B1];
    int e = (k == NB1 - 1) ? N_EDGES : bhofs[(k + 1) * B1];
    hist[t] = 0;
    __syncthreads();
    for (int i = s + t; i < e; i += 256)
        atomicAdd(&hist[(ebuf1[i] >> 16) & 255], 1);
    __syncthreads();
    int v = hist[t];
    scn[t] = v;
    __syncthreads();
    for (int off = 1; off < 256; off <<= 1) {
        int add = (t >= off) ? scn[t - off] : 0;
        __syncthreads();
        scn[t] += add;
        __syncthreads();
    }
    int ex = scn[t] - v;                 // exclusive scan
    int node = k * 256 + t;
    if (node < N_NODES) row_start[node] = s + ex;
    if (k == NB1 - 1 && t == 0) row_start[N_NODES] = N_EDGES;
    cur[t] = s + ex;
    __syncthreads();
    for (int i = s + t; i < e; i += 256) {
        uint_t p = ebuf1[i];
        int pos = atomicAdd(&cur[(p >> 16) & 255], 1);
        ebuf[pos] = (int)(p & 0xffffu);
    }
}

// ---------------------------------------------------------------------------
// Mean aggregation, 2-phase line-aligned: phase = blockIdx.y covers 64
// features = 128 B = exactly one L2 line per edge per phase (r8's 64 B
// version double-fetched lines across phases). Per-phase gather table
// 6.4 MB -> fewer L2 capacity misses. 8 groups x 8 lanes, uint4/lane ->
// 8 edges in flight per wave step. Merge via shfl_xor 8/16/32.
// ---------------------------------------------------------------------------
__global__ __launch_bounds__(256) void agg_kernel(const ushort_t* __restrict__ xb,
                                                  const int* __restrict__ row_start,
                                                  const int* __restrict__ ebuf,
                                                  ushort_t* __restrict__ agg_hi,
                                                  ushort_t* __restrict__ agg_lo) {
    int node = blockIdx.x * 4 + (threadIdx.x >> 6);   // grid.x*4 == N_NODES
    int phase = blockIdx.y;                            // 0 or 1
    int lane = threadIdx.x & 63;
    int grp = lane >> 3, fl = lane & 7;               // 8 groups x 8 lanes
    int s = row_start[node], e = row_start[node + 1];
    float a0=0.f,a1=0.f,a2=0.f,a3=0.f,a4=0.f,a5=0.f,a6=0.f,a7=0.f;
    const uint4* x8 = (const uint4*)xb;               // row = 16 x uint4
    int cofs = phase * 8 + fl;                        // uint4 index within row
    for (int i = s; i < e; i += 64) {
        int nloc = e - i; if (nloc > 64) nloc = 64;
        int src_l = (i + lane < e) ? ebuf[i + lane] : 0;
        int jmax = (nloc + 7) >> 3;
        #pragma unroll 2
        for (int j = 0; j < jmax; j++) {
            int slot = j * 8 + grp;                   // <= 63 always
            int src = __shfl(src_l, slot, 64);
            if (slot < nloc) {
                uint4 v = x8[(size_t)src * 16 + cofs];
                a0 += __uint_as_float(v.x << 16);
                a1 += __uint_as_float(v.x & 0xffff0000u);
                a2 += __uint_as_float(v.y << 16);
                a3 += __uint_as_float(v.y & 0xffff0000u);
                a4 += __uint_as_float(v.z << 16);
                a5 += __uint_as_float(v.z & 0xffff0000u);
                a6 += __uint_as_float(v.w << 16);
                a7 += __uint_as_float(v.w & 0xffff0000u);
            }
        }
    }
    #pragma unroll
    for (int off = 8; off <= 32; off <<= 1) {
        a0 += __shfl_xor(a0, off, 64);
        a1 += __shfl_xor(a1, off, 64);
        a2 += __shfl_xor(a2, off, 64);
        a3 += __shfl_xor(a3, off, 64);
        a4 += __shfl_xor(a4, off, 64);
        a5 += __shfl_xor(a5, off, 64);
        a6 += __shfl_xor(a6, off, 64);
        a7 += __shfl_xor(a7, off, 64);
    }
    if (grp == 0) {
        float inv = (e > s) ? 1.0f / (float)(e - s) : 0.0f;   // deg==0 -> agg = 0
        float v[8] = {a0*inv,a1*inv,a2*inv,a3*inv,a4*inv,a5*inv,a6*inv,a7*inv};
        uint_t h[8], l[8];
        #pragma unroll
        for (int k = 0; k < 8; k++) bf_split(v[k], h[k], l[k]);
        uint4 ho, lo;
        ho.x = h[0] | (h[1] << 16); ho.y = h[2] | (h[3] << 16);
        ho.z = h[4] | (h[5] << 16); ho.w = h[6] | (h[7] << 16);
        lo.x = l[0] | (l[1] << 16); lo.y = l[2] | (l[3] << 16);
        lo.z = l[4] | (l[5] << 16); lo.w = l[6] | (l[7] << 16);
        ((uint4*)agg_hi)[(size_t)node * 16 + cofs] = ho;
        ((uint4*)agg_lo)[(size_t)node * 16 + cofs] = lo;
    }
}

// ---------------------------------------------------------------------------
// MFMA GEMM: xout = relu(agg @ Wl^T + x @ Wr^T + b)
// A-side split-bf16 (hi+lo), weights bf16-hi only (4 MFMA terms/tile).
// Block 256 = 4 waves x 16 rows = 64 rows/block; LDS 64KB -> 2 blocks/CU.
// LDS XOR chunk swizzle: chunk ch of row r at ch^(r&7).
// Fragment maps (verified r2): A lane holds M[m=lane&15][k=quad*8+j];
// C/D col=lane&15, row=quad*4+reg.
// ---------------------------------------------------------------------------
__global__ __launch_bounds__(256, 2) void sage_gemm_mfma(
        const ushort_t* __restrict__ agg_hi, const ushort_t* __restrict__ agg_lo,
        const ushort_t* __restrict__ x_hi,   const ushort_t* __restrict__ x_lo,
        const ushort_t* __restrict__ wl_hi,  const ushort_t* __restrict__ wr_hi,
        const float* __restrict__ bias,
        ushort_t* __restrict__ out_hi, ushort_t* __restrict__ out_lo, int nrows) {
    __shared__ ushort_t whi_s[2][16384];    // 64 KB: [0]=Wl_hi, [1]=Wr_hi (swizzled)
    int t = threadIdx.x;
    for (int i = t; i < 4096; i += 256) {   // 2 arrays x 128 rows x 16 chunks
        int a = i >> 11, rem = i & 2047, row = rem >> 4, ch = rem & 15;
        int sw = ch ^ (row & 7);
        const ushort_t* srcp = a ? wr_hi : wl_hi;
        uint4 v = *(const uint4*)(srcp + row * DIM + ch * 8);
        *(uint4*)((char*)&whi_s[a][0] + row * 256 + sw * 16) = v;
    }
    __syncthreads();

    int wave = t >> 6, lane = t & 63;
    int ml = lane & 15, quad = lane >> 4;
    int m0 = blockIdx.x * 64 + wave * 16;
    int row = m0 + ml;
    int rowc = (row < nrows) ? row : (nrows - 1);
    size_t abase = (size_t)rowc * DIM + quad * 8;

    f32x4 acc[8];
    #pragma unroll
    for (int i = 0; i < 8; i++) acc[i] = (f32x4)0.f;

    #pragma unroll
    for (int kc = 0; kc < DIM; kc += 32) {
        bf16x8 Aah = *(const bf16x8*)(agg_hi + abase + kc);
        bf16x8 Aal = *(const bf16x8*)(agg_lo + abase + kc);
        bf16x8 Axh = *(const bf16x8*)(x_hi   + abase + kc);
        bf16x8 Axl = *(const bf16x8*)(x_lo   + abase + kc);
        int kch = (kc >> 3) + quad;          // 16B-chunk index within row
        int sw16 = (kch ^ (ml & 7)) * 16;    // nrow&7 == ml&7 (n0*16 ≡ 0 mod 8)
        #pragma unroll
        for (int n0 = 0; n0 < 8; n0++) {
            int nrow = n0 * 16 + ml;
            bf16x8 b_lh = *(const bf16x8*)((const char*)&whi_s[0][0] + nrow * 256 + sw16);
            bf16x8 b_rh = *(const bf16x8*)((const char*)&whi_s[1][0] + nrow * 256 + sw16);
            f32x4 c = acc[n0];
            c = __builtin_amdgcn_mfma_f32_16x16x32_bf16(Aah, b_lh, c, 0, 0, 0);
            c = __builtin_amdgcn_mfma_f32_16x16x32_bf16(Aal, b_lh, c, 0, 0, 0);
            c = __builtin_amdgcn_mfma_f32_16x16x32_bf16(Axh, b_rh, c, 0, 0, 0);
            c = __builtin_amdgcn_mfma_f32_16x16x32_bf16(Axl, b_rh, c, 0, 0, 0);
            acc[n0] = c;
        }
    }

    #pragma unroll
    for (int n0 = 0; n0 < 8; n0++) {
        int col = n0 * 16 + ml;
        float bv = bias[col];
        #pragma unroll
        for (int r = 0; r < 4; r++) {
            int orow = m0 + quad * 4 + r;
            if (orow < nrows) {
                float v = fmaxf(acc[n0][r] + bv, 0.f);
                uint_t h, l;
                bf_split(v, h, l);
                out_hi[(size_t)orow * DIM + col] = (ushort_t)h;
                out_lo[(size_t)orow * DIM + col] = (ushort_t)l;
            }
        }
    }
}

// ---------------------------------------------------------------------------
// Fused mean-pool + FC (wave/graph), features reconstructed from hi/lo.
// ---------------------------------------------------------------------------
__global__ __launch_bounds__(256) void pool_fc(const ushort_t* __restrict__ x_hi,
                                               const ushort_t* __restrict__ x_lo,
                                               const int* __restrict__ gstart,
                                               const float* __restrict__ fc_w,
                                               const float* __restrict__ fc_b,
                                               float* __restrict__ out) {
    int g = blockIdx.x * 4 + (threadIdx.x >> 6);
    if (g >= N_GRAPHS) return;
    int lane = threadIdx.x & 63;
    int s = gstart[g], e = gstart[g + 1];
    float ax = 0.f, ay = 0.f;
    const uint_t* xh = (const uint_t*)x_hi;
    const uint_t* xl = (const uint_t*)x_lo;
    for (int i = s; i < e; i++) {
        uint_t h = xh[(size_t)i * 64 + lane];
        uint_t l = xl[(size_t)i * 64 + lane];
        ax += __uint_as_float(h << 16) + __uint_as_float(l << 16);
        ay += __uint_as_float(h & 0xffff0000u) + __uint_as_float(l & 0xffff0000u);
    }
    float inv = (e > s) ? 1.0f / (float)(e - s) : 0.0f;
    const float2* w2 = (const float2*)fc_w;
    float2 w = w2[lane];
    float sres = (ax * w.x + ay * w.y) * inv;
    for (int off = 32; off; off >>= 1) sres += __shfl_down(sres, off, 64);
    if (lane == 0) out[g] = sres + fc_b[0];
}

// ---------------------------------------------------------------------------
extern "C" void kernel_launch(void* const* d_in, const int* in_sizes, int n_in,
                              void* d_out, int out_size, void* d_ws, size_t ws_size,
                              hipStream_t stream) {
    const float* x     = (const float*)d_in[0];
    const int*   ei    = (const int*)d_in[1];
    const int*   batch = (const int*)d_in[2];
    const float* Wl[3] = {(const float*)d_in[3], (const float*)d_in[6], (const float*)d_in[9]};
    const float* bb[3] = {(const float*)d_in[4], (const float*)d_in[7], (const float*)d_in[10]};
    const float* Wr[3] = {(const float*)d_in[5], (const float*)d_in[8], (const float*)d_in[11]};
    const float* fc_w  = (const float*)d_in[12];
    const float* fc_b  = (const float*)d_in[13];
    float* out = (float*)d_out;

    char* p = (char*)d_ws;
    auto alloc = [&](size_t bytes) { char* r = p; p += (bytes + 255) & ~255ull; return r; };
    int* bh        = (int*)alloc((size_t)BH_N * 4);
    int* bhofs     = (int*)alloc((size_t)(BH_N + 1) * 4);
    int* bsum      = (int*)alloc((size_t)BH_BLK * 4);
    int* bofs      = (int*)alloc((size_t)BH_BLK * 4);
    uint_t* ebuf1  = (uint_t*)alloc((size_t)N_EDGES * 4);
    int* ebuf      = (int*)alloc((size_t)N_EDGES * 4);
    int* row_start = (int*)alloc((size_t)(N_NODES + 1) * 4);
    int* gstart    = (int*)alloc((size_t)(N_GRAPHS + 1) * 4);
    const size_t FB = (size_t)N_NODES * DIM * 2;     // feature buffer bytes (bf16)
    ushort_t* agg_hi = (ushort_t*)alloc(FB);
    ushort_t* agg_lo = (ushort_t*)alloc(FB);
    ushort_t* fh[3]  = {(ushort_t*)alloc(FB), (ushort_t*)alloc(FB), (ushort_t*)alloc(FB)};
    ushort_t* fl_[3] = {(ushort_t*)alloc(FB), (ushort_t*)alloc(FB), (ushort_t*)alloc(FB)};
    ushort_t* whi    = (ushort_t*)alloc((size_t)6 * 16384 * 2);

    const int* src = ei;
    const int* dst = ei + N_EDGES;

    prep_kernel<<<B1 + XS_BLOCKS + WS_BLOCKS + GB_BLOCKS, 256, 0, stream>>>(
        dst, bh, x, fh[0], fl_[0], Wl[0], Wr[0], Wl[1], Wr[1], Wl[2], Wr[2],
        whi, batch, gstart);
    block_reduce_n<<<BH_BLK, 256, 0, stream>>>(bh, bsum, BH_N);
    scan_tops_n<<<1, 64, 0, stream>>>(bsum, bofs, BH_BLK);
    block_scan_n<<<BH_BLK, SCAN_BLOCK, 0, stream>>>(bh, bofs, bhofs, BH_N);
    p1_scatter<<<B1, 256, 0, stream>>>(src, dst, bhofs, ebuf1);
    p2_sort<<<NB1, 256, 0, stream>>>(ebuf1, bhofs, row_start, ebuf);

    // buffers: layer0 in fh[0] -> out fh[1]; layer1 in fh[1] -> out fh[2]; layer2 in fh[2] -> out fh[1]
    int inb = 0;
    for (int l = 0; l < 3; l++) {
        int outb = (l == 0) ? 1 : (l == 1) ? 2 : 1;
        agg_kernel<<<dim3(N_NODES / 4, 2), 256, 0, stream>>>(fh[inb], row_start, ebuf, agg_hi, agg_lo);
        sage_gemm_mfma<<<(N_NODES + 63) / 64, 256, 0, stream>>>(
            agg_hi, agg_lo, fh[inb], fl_[inb],
            whi + (size_t)(2 * l) * 16384, whi + (size_t)(2 * l + 1) * 16384,
            bb[l], fh[outb], fl_[outb], N_NODES);
        inb = outb;
    }
    pool_fc<<<(N_GRAPHS + 3) / 4, 256, 0, stream>>>(fh[inb], fl_[inb], gstart, fc_w, fc_b, out);
}

// Round 11
// 449.899 us; speedup vs baseline: 1.0214x; 1.0214x over previous
//
#include <hip/hip_runtime.h>

#define N_NODES  50000
#define N_EDGES  1600000
#define DIM      128
#define N_GRAPHS 512
#define SCAN_BLOCK 1024
#define NB1   196        // coarse buckets = ceil(50000/256)
#define B1    256        // phase-1 blocks
#define CHUNK 6250       // edges per phase-1 block (256*6250 = 1.6M exactly)
#define BH_N  (NB1 * B1) // 50176
#define BH_BLK ((BH_N + SCAN_BLOCK - 1) / SCAN_BLOCK)  // 49
#define XS_BLOCKS 6250   // xsplit: 50000*128/4 / 256
#define WS_BLOCKS 384    // wsplit: 6*16384 / 256
#define GB_BLOCKS 196    // graph_bounds: ceil(50000/256)
#define OI_BLOCKS 2      // out-init: 512 graphs / 256

typedef unsigned int uint_t;
typedef unsigned short ushort_t;
typedef __attribute__((ext_vector_type(8))) short bf16x8;
typedef __attribute__((ext_vector_type(4))) float f32x4;

__device__ inline uint_t bf_rne(float f) {   // fp32 -> bf16 bits, round-nearest-even
    uint_t u = __float_as_uint(f);
    return (u + 0x7fffu + ((u >> 16) & 1u)) >> 16;
}

// split f into hi (bf16) and lo (bf16 of residual); f ~= hi + lo to ~2^-17 rel
__device__ inline void bf_split(float f, uint_t& h, uint_t& l) {
    h = bf_rne(f);
    float hf = __uint_as_float(h << 16);
    l = bf_rne(f - hf);
}

// ---------------------------------------------------------------------------
// Combined prep: p1_count + xsplit + wsplit + graph_bounds + out-init(fc_b),
// partitioned by blockIdx range. All parts only read kernel inputs.
// ---------------------------------------------------------------------------
__global__ __launch_bounds__(256) void prep_kernel(
        const int* __restrict__ dst, int* __restrict__ bh,
        const float* __restrict__ x, ushort_t* __restrict__ xh, ushort_t* __restrict__ xl,
        const float* w0, const float* w1, const float* w2,
        const float* w3, const float* w4, const float* w5,
        ushort_t* __restrict__ whi,
        const int* __restrict__ batch, int* __restrict__ gstart,
        const float* __restrict__ fc_b, float* __restrict__ out) {
    __shared__ int hist[NB1];
    int b = blockIdx.x, t = threadIdx.x;
    if (b < B1) {
        // --- p1_count: coarse histogram (dst>>8) for this edge chunk ---
        for (int i = t; i < NB1; i += 256) hist[i] = 0;
        __syncthreads();
        int base = b * CHUNK;
        for (int i = t; i < CHUNK; i += 256)
            atomicAdd(&hist[dst[base + i] >> 8], 1);
        __syncthreads();
        for (int i = t; i < NB1; i += 256) bh[i * B1 + b] = hist[i];
    } else if (b < B1 + XS_BLOCKS) {
        int i = (b - B1) * 256 + t;                 // exactly 1.6M float4 groups
        float4 v = ((const float4*)x)[i];
        uint_t h0,h1,h2,h3,l0,l1,l2,l3;
        bf_split(v.x,h0,l0); bf_split(v.y,h1,l1); bf_split(v.z,h2,l2); bf_split(v.w,h3,l3);
        uint2 ho; ho.x = h0 | (h1 << 16); ho.y = h2 | (h3 << 16);
        uint2 lo; lo.x = l0 | (l1 << 16); lo.y = l2 | (l3 << 16);
        ((uint2*)xh)[i] = ho;
        ((uint2*)xl)[i] = lo;
    } else if (b < B1 + XS_BLOCKS + WS_BLOCKS) {
        int i = (b - B1 - XS_BLOCKS) * 256 + t;     // exactly 6*16384
        int ws = i >> 14, off = i & 16383;
        const float* w = (ws == 0) ? w0 : (ws == 1) ? w1 : (ws == 2) ? w2
                       : (ws == 3) ? w3 : (ws == 4) ? w4 : w5;
        whi[i] = (ushort_t)bf_rne(w[off]);
    } else if (b < B1 + XS_BLOCKS + WS_BLOCKS + GB_BLOCKS) {
        int i = (b - B1 - XS_BLOCKS - WS_BLOCKS) * 256 + t;
        if (i < N_NODES) {
            int bb = batch[i];
            int prev = (i == 0) ? -1 : batch[i - 1];
            for (int g = prev + 1; g <= bb; g++) gstart[g] = i;
            if (i == 0) {
                int last = batch[N_NODES - 1];
                for (int g = last + 1; g <= N_GRAPHS; g++) gstart[g] = N_NODES;
            }
        }
    } else {
        int i = (b - B1 - XS_BLOCKS - WS_BLOCKS - GB_BLOCKS) * 256 + t;
        if (i < N_GRAPHS) out[i] = fc_b[0];   // pool accumulator base
    }
}

// hierarchical scan step 1: per-tile sums over bh (BH_N entries)
__global__ void block_reduce_n(const int* __restrict__ in, int* __restrict__ bsum, int n) {
    __shared__ int red[256];
    int b = blockIdx.x, t = threadIdx.x;
    int base = b * SCAN_BLOCK;
    int s = 0;
    for (int i = t; i < SCAN_BLOCK; i += 256) {
        int idx = base + i;
        s += (idx < n) ? in[idx] : 0;
    }
    red[t] = s; __syncthreads();
    for (int off = 128; off; off >>= 1) {
        if (t < off) red[t] += red[t + off];
        __syncthreads();
    }
    if (t == 0) bsum[b] = red[0];
}

// step 2 (merged): each block wave-scans the <=64 tile sums for its base, then
// scans its own tile. Replaces scan_tops_n + block_scan_n (one fewer dispatch).
__global__ void scan_finalize(const int* __restrict__ in, const int* __restrict__ bsum,
                              int* __restrict__ ofs, int n, int nblk) {
    __shared__ int small[64];
    __shared__ int tmp[SCAN_BLOCK];
    int b = blockIdx.x, t = threadIdx.x;
    if (t < 64) {
        int v = (t < nblk) ? bsum[t] : 0;
        for (int off = 1; off < 64; off <<= 1) {
            int u = __shfl_up(v, off, 64);
            if (t >= off) v += u;
        }
        small[t] = v;                        // inclusive scan of tile sums
    }
    __syncthreads();
    int base = (b == 0) ? 0 : small[b - 1];
    int i = b * SCAN_BLOCK + t;
    tmp[t] = (i < n) ? in[i] : 0;
    __syncthreads();
    for (int off = 1; off < SCAN_BLOCK; off <<= 1) {
        int add = (t >= off) ? tmp[t - off] : 0;
        __syncthreads();
        tmp[t] += add;
        __syncthreads();
    }
    if (i < n) ofs[i + 1] = tmp[t] + base;
    if (i == 0) ofs[0] = 0;
}

__global__ __launch_bounds__(256) void p1_scatter(const int* __restrict__ src,
                                                  const int* __restrict__ dst,
                                                  const int* __restrict__ bhofs,
                                                  uint_t* __restrict__ ebuf1) {
    __shared__ int cur[NB1];
    int b = blockIdx.x, t = threadIdx.x;
    for (int i = t; i < NB1; i += 256) cur[i] = bhofs[i * B1 + b];
    __syncthreads();
    int base = b * CHUNK;
    for (int i = t; i < CHUNK; i += 256) {
        int d = dst[base + i];
        int pos = atomicAdd(&cur[d >> 8], 1);
        ebuf1[pos] = (uint_t)src[base + i] | ((uint_t)(d & 255) << 16);
    }
}

// one block per coarse bucket: hist over low byte -> row_start + final scatter.
__global__ __launch_bounds__(256) void p2_sort(const uint_t* __restrict__ ebuf1,
                                               const int* __restrict__ bhofs,
                                               int* __restrict__ row_start,
                                               int* __restrict__ ebuf) {
    __shared__ int hist[256];
    __shared__ int scn[256];
    __shared__ int cur[256];
    int k = blockIdx.x, t = threadIdx.x;
    int s = bhofs[k * B1];
    int e = (k == NB1 - 1) ? N_EDGES : bhofs[(k + 1) * B1];
    hist[t] = 0;
    __syncthreads();
    for (int i = s + t; i < e; i += 256)
        atomicAdd(&hist[(ebuf1[i] >> 16) & 255], 1);
    __syncthreads();
    int v = hist[t];
    scn[t] = v;
    __syncthreads();
    for (int off = 1; off < 256; off <<= 1) {
        int add = (t >= off) ? scn[t - off] : 0;
        __syncthreads();
        scn[t] += add;
        __syncthreads();
    }
    int ex = scn[t] - v;                 // exclusive scan
    int node = k * 256 + t;
    if (node < N_NODES) row_start[node] = s + ex;
    if (k == NB1 - 1 && t == 0) row_start[N_NODES] = N_EDGES;
    cur[t] = s + ex;
    __syncthreads();
    for (int i = s + t; i < e; i += 256) {
        uint_t p = ebuf1[i];
        int pos = atomicAdd(&cur[(p >> 16) & 255], 1);
        ebuf[pos] = (int)(p & 0xffffu);
    }
}

// ---------------------------------------------------------------------------
// Mean aggregation (r9 one-pass, best measured): one wave per node.
// 16-lane groups x uint4 (16 B) -> full 256 B row per group, 4 edges in
// flight per wave step. Group-merge via shfl_xor; group 0 writes hi/lo split.
// ---------------------------------------------------------------------------
__global__ __launch_bounds__(256) void agg_kernel(const ushort_t* __restrict__ xb,
                                                  const int* __restrict__ row_start,
                                                  const int* __restrict__ ebuf,
                                                  ushort_t* __restrict__ agg_hi,
                                                  ushort_t* __restrict__ agg_lo) {
    int node = blockIdx.x * 4 + (threadIdx.x >> 6);
    if (node >= N_NODES) return;
    int lane = threadIdx.x & 63;
    int grp = lane >> 4, fl = lane & 15;
    int s = row_start[node], e = row_start[node + 1];
    float a0=0.f,a1=0.f,a2=0.f,a3=0.f,a4=0.f,a5=0.f,a6=0.f,a7=0.f;
    const uint4* x8 = (const uint4*)xb;              // row = 16 x uint4 (8 bf16 each)
    for (int i = s; i < e; i += 64) {
        int nloc = e - i; if (nloc > 64) nloc = 64;
        int src_l = (i + lane < e) ? ebuf[i + lane] : 0;
        int jmax = (nloc + 3) & ~3;
        #pragma unroll 4
        for (int j = 0; j < jmax; j += 4) {
            int slot = j + grp;
            int src = __shfl(src_l, slot & 63, 64);
            if (slot < nloc) {
                uint4 v = x8[(size_t)src * 16 + fl];
                a0 += __uint_as_float(v.x << 16);
                a1 += __uint_as_float(v.x & 0xffff0000u);
                a2 += __uint_as_float(v.y << 16);
                a3 += __uint_as_float(v.y & 0xffff0000u);
                a4 += __uint_as_float(v.z << 16);
                a5 += __uint_as_float(v.z & 0xffff0000u);
                a6 += __uint_as_float(v.w << 16);
                a7 += __uint_as_float(v.w & 0xffff0000u);
            }
        }
    }
    a0 += __shfl_xor(a0, 16, 64); a0 += __shfl_xor(a0, 32, 64);
    a1 += __shfl_xor(a1, 16, 64); a1 += __shfl_xor(a1, 32, 64);
    a2 += __shfl_xor(a2, 16, 64); a2 += __shfl_xor(a2, 32, 64);
    a3 += __shfl_xor(a3, 16, 64); a3 += __shfl_xor(a3, 32, 64);
    a4 += __shfl_xor(a4, 16, 64); a4 += __shfl_xor(a4, 32, 64);
    a5 += __shfl_xor(a5, 16, 64); a5 += __shfl_xor(a5, 32, 64);
    a6 += __shfl_xor(a6, 16, 64); a6 += __shfl_xor(a6, 32, 64);
    a7 += __shfl_xor(a7, 16, 64); a7 += __shfl_xor(a7, 32, 64);
    if (grp == 0) {
        float inv = (e > s) ? 1.0f / (float)(e - s) : 0.0f;   // deg==0 -> agg = 0
        float v[8] = {a0*inv,a1*inv,a2*inv,a3*inv,a4*inv,a5*inv,a6*inv,a7*inv};
        uint_t h[8], l[8];
        #pragma unroll
        for (int k = 0; k < 8; k++) bf_split(v[k], h[k], l[k]);
        uint4 ho, lo;
        ho.x = h[0] | (h[1] << 16); ho.y = h[2] | (h[3] << 16);
        ho.z = h[4] | (h[5] << 16); ho.w = h[6] | (h[7] << 16);
        lo.x = l[0] | (l[1] << 16); lo.y = l[2] | (l[3] << 16);
        lo.z = l[4] | (l[5] << 16); lo.w = l[6] | (l[7] << 16);
        ((uint4*)agg_hi)[(size_t)node * 16 + fl] = ho;
        ((uint4*)agg_lo)[(size_t)node * 16 + fl] = lo;
    }
}

// ---------------------------------------------------------------------------
// MFMA GEMM: xout = relu(agg @ Wl^T + x @ Wr^T + b)
// A-side split-bf16 (hi+lo), weights bf16-hi only (4 MFMA terms/tile).
// Block 256 = 4 waves x 16 rows = 64 rows/block; LDS 64KB -> 2 blocks/CU.
// If pool_out != null (last layer): instead of storing features, compute
// per-row dot with fc_w, 16-lane reduce, atomicAdd(out[batch[row]], dot/cnt).
// Fragment maps (verified r2): A lane holds M[m=lane&15][k=quad*8+j];
// C/D col=lane&15, row=quad*4+reg.
// ---------------------------------------------------------------------------
__global__ __launch_bounds__(256, 2) void sage_gemm_mfma(
        const ushort_t* __restrict__ agg_hi, const ushort_t* __restrict__ agg_lo,
        const ushort_t* __restrict__ x_hi,   const ushort_t* __restrict__ x_lo,
        const ushort_t* __restrict__ wl_hi,  const ushort_t* __restrict__ wr_hi,
        const float* __restrict__ bias,
        ushort_t* __restrict__ out_hi, ushort_t* __restrict__ out_lo,
        const int* __restrict__ batch, const int* __restrict__ gstart,
        const float* __restrict__ fc_w, float* __restrict__ pool_out, int nrows) {
    __shared__ ushort_t whi_s[2][16384];    // 64 KB: [0]=Wl_hi, [1]=Wr_hi (swizzled)
    int t = threadIdx.x;
    for (int i = t; i < 4096; i += 256) {   // 2 arrays x 128 rows x 16 chunks
        int a = i >> 11, rem = i & 2047, row = rem >> 4, ch = rem & 15;
        int sw = ch ^ (row & 7);
        const ushort_t* srcp = a ? wr_hi : wl_hi;
        uint4 v = *(const uint4*)(srcp + row * DIM + ch * 8);
        *(uint4*)((char*)&whi_s[a][0] + row * 256 + sw * 16) = v;
    }
    __syncthreads();

    int wave = t >> 6, lane = t & 63;
    int ml = lane & 15, quad = lane >> 4;
    int m0 = blockIdx.x * 64 + wave * 16;
    int row = m0 + ml;
    int rowc = (row < nrows) ? row : (nrows - 1);
    size_t abase = (size_t)rowc * DIM + quad * 8;

    f32x4 acc[8];
    #pragma unroll
    for (int i = 0; i < 8; i++) acc[i] = (f32x4)0.f;

    #pragma unroll
    for (int kc = 0; kc < DIM; kc += 32) {
        bf16x8 Aah = *(const bf16x8*)(agg_hi + abase + kc);
        bf16x8 Aal = *(const bf16x8*)(agg_lo + abase + kc);
        bf16x8 Axh = *(const bf16x8*)(x_hi   + abase + kc);
        bf16x8 Axl = *(const bf16x8*)(x_lo   + abase + kc);
        int kch = (kc >> 3) + quad;          // 16B-chunk index within row
        int sw16 = (kch ^ (ml & 7)) * 16;    // nrow&7 == ml&7 (n0*16 ≡ 0 mod 8)
        #pragma unroll
        for (int n0 = 0; n0 < 8; n0++) {
            int nrow = n0 * 16 + ml;
            bf16x8 b_lh = *(const bf16x8*)((const char*)&whi_s[0][0] + nrow * 256 + sw16);
            bf16x8 b_rh = *(const bf16x8*)((const char*)&whi_s[1][0] + nrow * 256 + sw16);
            f32x4 c = acc[n0];
            c = __builtin_amdgcn_mfma_f32_16x16x32_bf16(Aah, b_lh, c, 0, 0, 0);
            c = __builtin_amdgcn_mfma_f32_16x16x32_bf16(Aal, b_lh, c, 0, 0, 0);
            c = __builtin_amdgcn_mfma_f32_16x16x32_bf16(Axh, b_rh, c, 0, 0, 0);
            c = __builtin_amdgcn_mfma_f32_16x16x32_bf16(Axl, b_rh, c, 0, 0, 0);
            acc[n0] = c;
        }
    }

    if (pool_out) {
        // fused mean-pool + FC: per-row dot(relu(acc+bias), fc_w)
        float rd[4] = {0.f, 0.f, 0.f, 0.f};
        #pragma unroll
        for (int n0 = 0; n0 < 8; n0++) {
            int col = n0 * 16 + ml;
            float bv = bias[col];
            float w  = fc_w[col];
            #pragma unroll
            for (int r = 0; r < 4; r++)
                rd[r] += fmaxf(acc[n0][r] + bv, 0.f) * w;
        }
        #pragma unroll
        for (int r = 0; r < 4; r++) {
            #pragma unroll
            for (int off = 1; off < 16; off <<= 1)
                rd[r] += __shfl_xor(rd[r], off, 64);
            int orow = m0 + quad * 4 + r;
            if (orow < nrows && ml == 0) {
                int g = batch[orow];
                float cnt = (float)(gstart[g + 1] - gstart[g]);
                atomicAdd(&pool_out[g], rd[r] / cnt);
            }
        }
    } else {
        #pragma unroll
        for (int n0 = 0; n0 < 8; n0++) {
            int col = n0 * 16 + ml;
            float bv = bias[col];
            #pragma unroll
            for (int r = 0; r < 4; r++) {
                int orow = m0 + quad * 4 + r;
                if (orow < nrows) {
                    float v = fmaxf(acc[n0][r] + bv, 0.f);
                    uint_t h, l;
                    bf_split(v, h, l);
                    out_hi[(size_t)orow * DIM + col] = (ushort_t)h;
                    out_lo[(size_t)orow * DIM + col] = (ushort_t)l;
                }
            }
        }
    }
}

// ---------------------------------------------------------------------------
extern "C" void kernel_launch(void* const* d_in, const int* in_sizes, int n_in,
                              void* d_out, int out_size, void* d_ws, size_t ws_size,
                              hipStream_t stream) {
    const float* x     = (const float*)d_in[0];
    const int*   ei    = (const int*)d_in[1];
    const int*   batch = (const int*)d_in[2];
    const float* Wl[3] = {(const float*)d_in[3], (const float*)d_in[6], (const float*)d_in[9]};
    const float* bb[3] = {(const float*)d_in[4], (const float*)d_in[7], (const float*)d_in[10]};
    const float* Wr[3] = {(const float*)d_in[5], (const float*)d_in[8], (const float*)d_in[11]};
    const float* fc_w  = (const float*)d_in[12];
    const float* fc_b  = (const float*)d_in[13];
    float* out = (float*)d_out;

    char* p = (char*)d_ws;
    auto alloc = [&](size_t bytes) { char* r = p; p += (bytes + 255) & ~255ull; return r; };
    int* bh        = (int*)alloc((size_t)BH_N * 4);
    int* bhofs     = (int*)alloc((size_t)(BH_N + 1) * 4);
    int* bsum      = (int*)alloc((size_t)BH_BLK * 4);
    uint_t* ebuf1  = (uint_t*)alloc((size_t)N_EDGES * 4);
    int* ebuf      = (int*)alloc((size_t)N_EDGES * 4);
    int* row_start = (int*)alloc((size_t)(N_NODES + 1) * 4);
    int* gstart    = (int*)alloc((size_t)(N_GRAPHS + 1) * 4);
    const size_t FB = (size_t)N_NODES * DIM * 2;     // feature buffer bytes (bf16)
    ushort_t* agg_hi = (ushort_t*)alloc(FB);
    ushort_t* agg_lo = (ushort_t*)alloc(FB);
    ushort_t* fh[3]  = {(ushort_t*)alloc(FB), (ushort_t*)alloc(FB), (ushort_t*)alloc(FB)};
    ushort_t* fl_[3] = {(ushort_t*)alloc(FB), (ushort_t*)alloc(FB), (ushort_t*)alloc(FB)};
    ushort_t* whi    = (ushort_t*)alloc((size_t)6 * 16384 * 2);

    const int* src = ei;
    const int* dst = ei + N_EDGES;

    prep_kernel<<<B1 + XS_BLOCKS + WS_BLOCKS + GB_BLOCKS + OI_BLOCKS, 256, 0, stream>>>(
        dst, bh, x, fh[0], fl_[0], Wl[0], Wr[0], Wl[1], Wr[1], Wl[2], Wr[2],
        whi, batch, gstart, fc_b, out);
    block_reduce_n<<<BH_BLK, 256, 0, stream>>>(bh, bsum, BH_N);
    scan_finalize<<<BH_BLK, SCAN_BLOCK, 0, stream>>>(bh, bsum, bhofs, BH_N, BH_BLK);
    p1_scatter<<<B1, 256, 0, stream>>>(src, dst, bhofs, ebuf1);
    p2_sort<<<NB1, 256, 0, stream>>>(ebuf1, bhofs, row_start, ebuf);

    // buffers: layer0 in fh[0] -> out fh[1]; layer1 in fh[1] -> out fh[2];
    // layer2 output fused into pool (no feature store).
    int inb = 0;
    for (int l = 0; l < 3; l++) {
        int outb = (l == 0) ? 1 : 2;
        agg_kernel<<<(N_NODES + 3) / 4, 256, 0, stream>>>(fh[inb], row_start, ebuf, agg_hi, agg_lo);
        sage_gemm_mfma<<<(N_NODES + 63) / 64, 256, 0, stream>>>(
            agg_hi, agg_lo, fh[inb], fl_[inb],
            whi + (size_t)(2 * l) * 16384, whi + (size_t)(2 * l + 1) * 16384,
            bb[l], fh[outb], fl_[outb],
            batch, gstart, fc_w, (l == 2) ? out : (float*)nullptr, N_NODES);
        inb = outb;
    }
}

// Round 12
// 392.277 us; speedup vs baseline: 1.1715x; 1.1469x over previous
//
#include <hip/hip_runtime.h>

#define N_NODES  50000
#define N_EDGES  1600000
#define DIM      128
#define N_GRAPHS 512
#define SCAN_BLOCK 1024
#define NB1   196        // coarse buckets = ceil(50000/256)
#define B1    256        // phase-1 blocks
#define CHUNK 6250       // edges per phase-1 block (256*6250 = 1.6M exactly)
#define BH_N  (NB1 * B1) // 50176
#define BH_BLK ((BH_N + SCAN_BLOCK - 1) / SCAN_BLOCK)  // 49
#define XS_BLOCKS 6250   // xsplit: 50000*128/4 / 256
#define WS_BLOCKS 384    // wsplit: 6*16384 / 256
#define GB_BLOCKS 196    // graph_bounds: ceil(50000/256)
#define OI_BLOCKS 2      // out-init: 512 graphs / 256

typedef unsigned int uint_t;
typedef unsigned short ushort_t;
typedef __attribute__((ext_vector_type(8))) short bf16x8;
typedef __attribute__((ext_vector_type(4))) float f32x4;

__device__ inline uint_t bf_rne(float f) {   // fp32 -> bf16 bits, round-nearest-even
    uint_t u = __float_as_uint(f);
    return (u + 0x7fffu + ((u >> 16) & 1u)) >> 16;
}

// split f into hi (bf16) and lo (bf16 of residual); f ~= hi + lo to ~2^-17 rel
__device__ inline void bf_split(float f, uint_t& h, uint_t& l) {
    h = bf_rne(f);
    float hf = __uint_as_float(h << 16);
    l = bf_rne(f - hf);
}

// ---------------------------------------------------------------------------
// Combined prep: p1_count + xsplit + wsplit + graph_bounds + out-init(fc_b),
// partitioned by blockIdx range. All parts only read kernel inputs.
// ---------------------------------------------------------------------------
__global__ __launch_bounds__(256) void prep_kernel(
        const int* __restrict__ dst, int* __restrict__ bh,
        const float* __restrict__ x, ushort_t* __restrict__ xh, ushort_t* __restrict__ xl,
        const float* w0, const float* w1, const float* w2,
        const float* w3, const float* w4, const float* w5,
        ushort_t* __restrict__ whi,
        const int* __restrict__ batch, int* __restrict__ gstart,
        const float* __restrict__ fc_b, float* __restrict__ out) {
    __shared__ int hist[NB1];
    int b = blockIdx.x, t = threadIdx.x;
    if (b < B1) {
        // --- p1_count: coarse histogram (dst>>8) for this edge chunk ---
        for (int i = t; i < NB1; i += 256) hist[i] = 0;
        __syncthreads();
        int base = b * CHUNK;
        for (int i = t; i < CHUNK; i += 256)
            atomicAdd(&hist[dst[base + i] >> 8], 1);
        __syncthreads();
        for (int i = t; i < NB1; i += 256) bh[i * B1 + b] = hist[i];
    } else if (b < B1 + XS_BLOCKS) {
        int i = (b - B1) * 256 + t;                 // exactly 1.6M float4 groups
        float4 v = ((const float4*)x)[i];
        uint_t h0,h1,h2,h3,l0,l1,l2,l3;
        bf_split(v.x,h0,l0); bf_split(v.y,h1,l1); bf_split(v.z,h2,l2); bf_split(v.w,h3,l3);
        uint2 ho; ho.x = h0 | (h1 << 16); ho.y = h2 | (h3 << 16);
        uint2 lo; lo.x = l0 | (l1 << 16); lo.y = l2 | (l3 << 16);
        ((uint2*)xh)[i] = ho;
        ((uint2*)xl)[i] = lo;
    } else if (b < B1 + XS_BLOCKS + WS_BLOCKS) {
        int i = (b - B1 - XS_BLOCKS) * 256 + t;     // exactly 6*16384
        int ws = i >> 14, off = i & 16383;
        const float* w = (ws == 0) ? w0 : (ws == 1) ? w1 : (ws == 2) ? w2
                       : (ws == 3) ? w3 : (ws == 4) ? w4 : w5;
        whi[i] = (ushort_t)bf_rne(w[off]);
    } else if (b < B1 + XS_BLOCKS + WS_BLOCKS + GB_BLOCKS) {
        int i = (b - B1 - XS_BLOCKS - WS_BLOCKS) * 256 + t;
        if (i < N_NODES) {
            int bb = batch[i];
            int prev = (i == 0) ? -1 : batch[i - 1];
            for (int g = prev + 1; g <= bb; g++) gstart[g] = i;
            if (i == 0) {
                int last = batch[N_NODES - 1];
                for (int g = last + 1; g <= N_GRAPHS; g++) gstart[g] = N_NODES;
            }
        }
    } else {
        int i = (b - B1 - XS_BLOCKS - WS_BLOCKS - GB_BLOCKS) * 256 + t;
        if (i < N_GRAPHS) out[i] = fc_b[0];   // pool accumulator base
    }
}

// hierarchical scan step 1: per-tile sums over bh (BH_N entries)
__global__ void block_reduce_n(const int* __restrict__ in, int* __restrict__ bsum, int n) {
    __shared__ int red[256];
    int b = blockIdx.x, t = threadIdx.x;
    int base = b * SCAN_BLOCK;
    int s = 0;
    for (int i = t; i < SCAN_BLOCK; i += 256) {
        int idx = base + i;
        s += (idx < n) ? in[idx] : 0;
    }
    red[t] = s; __syncthreads();
    for (int off = 128; off; off >>= 1) {
        if (t < off) red[t] += red[t + off];
        __syncthreads();
    }
    if (t == 0) bsum[b] = red[0];
}

// step 2 (merged): each block wave-scans the <=64 tile sums for its base, then
// scans its own tile.
__global__ void scan_finalize(const int* __restrict__ in, const int* __restrict__ bsum,
                              int* __restrict__ ofs, int n, int nblk) {
    __shared__ int small[64];
    __shared__ int tmp[SCAN_BLOCK];
    int b = blockIdx.x, t = threadIdx.x;
    if (t < 64) {
        int v = (t < nblk) ? bsum[t] : 0;
        for (int off = 1; off < 64; off <<= 1) {
            int u = __shfl_up(v, off, 64);
            if (t >= off) v += u;
        }
        small[t] = v;                        // inclusive scan of tile sums
    }
    __syncthreads();
    int base = (b == 0) ? 0 : small[b - 1];
    int i = b * SCAN_BLOCK + t;
    tmp[t] = (i < n) ? in[i] : 0;
    __syncthreads();
    for (int off = 1; off < SCAN_BLOCK; off <<= 1) {
        int add = (t >= off) ? tmp[t - off] : 0;
        __syncthreads();
        tmp[t] += add;
        __syncthreads();
    }
    if (i < n) ofs[i + 1] = tmp[t] + base;
    if (i == 0) ofs[0] = 0;
}

__global__ __launch_bounds__(256) void p1_scatter(const int* __restrict__ src,
                                                  const int* __restrict__ dst,
                                                  const int* __restrict__ bhofs,
                                                  uint_t* __restrict__ ebuf1) {
    __shared__ int cur[NB1];
    int b = blockIdx.x, t = threadIdx.x;
    for (int i = t; i < NB1; i += 256) cur[i] = bhofs[i * B1 + b];
    __syncthreads();
    int base = b * CHUNK;
    for (int i = t; i < CHUNK; i += 256) {
        int d = dst[base + i];
        int pos = atomicAdd(&cur[d >> 8], 1);
        ebuf1[pos] = (uint_t)src[base + i] | ((uint_t)(d & 255) << 16);
    }
}

// one block per coarse bucket: hist over low byte -> row_start + final scatter.
__global__ __launch_bounds__(256) void p2_sort(const uint_t* __restrict__ ebuf1,
                                               const int* __restrict__ bhofs,
                                               int* __restrict__ row_start,
                                               int* __restrict__ ebuf) {
    __shared__ int hist[256];
    __shared__ int scn[256];
    __shared__ int cur[256];
    int k = blockIdx.x, t = threadIdx.x;
    int s = bhofs[k * B1];
    int e = (k == NB1 - 1) ? N_EDGES : bhofs[(k + 1) * B1];
    hist[t] = 0;
    __syncthreads();
    for (int i = s + t; i < e; i += 256)
        atomicAdd(&hist[(ebuf1[i] >> 16) & 255], 1);
    __syncthreads();
    int v = hist[t];
    scn[t] = v;
    __syncthreads();
    for (int off = 1; off < 256; off <<= 1) {
        int add = (t >= off) ? scn[t - off] : 0;
        __syncthreads();
        scn[t] += add;
        __syncthreads();
    }
    int ex = scn[t] - v;                 // exclusive scan
    int node = k * 256 + t;
    if (node < N_NODES) row_start[node] = s + ex;
    if (k == NB1 - 1 && t == 0) row_start[N_NODES] = N_EDGES;
    cur[t] = s + ex;
    __syncthreads();
    for (int i = s + t; i < e; i += 256) {
        uint_t p = ebuf1[i];
        int pos = atomicAdd(&cur[(p >> 16) & 255], 1);
        ebuf[pos] = (int)(p & 0xffffu);
    }
}

// ---------------------------------------------------------------------------
// Mean aggregation (r9 one-pass, best measured): one wave per node.
// 16-lane groups x uint4 (16 B) -> full 256 B row per group, 4 edges in
// flight per wave step. Group-merge via shfl_xor; group 0 writes hi/lo split.
// ---------------------------------------------------------------------------
__global__ __launch_bounds__(256) void agg_kernel(const ushort_t* __restrict__ xb,
                                                  const int* __restrict__ row_start,
                                                  const int* __restrict__ ebuf,
                                                  ushort_t* __restrict__ agg_hi,
                                                  ushort_t* __restrict__ agg_lo) {
    int node = blockIdx.x * 4 + (threadIdx.x >> 6);
    if (node >= N_NODES) return;
    int lane = threadIdx.x & 63;
    int grp = lane >> 4, fl = lane & 15;
    int s = row_start[node], e = row_start[node + 1];
    float a0=0.f,a1=0.f,a2=0.f,a3=0.f,a4=0.f,a5=0.f,a6=0.f,a7=0.f;
    const uint4* x8 = (const uint4*)xb;              // row = 16 x uint4 (8 bf16 each)
    for (int i = s; i < e; i += 64) {
        int nloc = e - i; if (nloc > 64) nloc = 64;
        int src_l = (i + lane < e) ? ebuf[i + lane] : 0;
        int jmax = (nloc + 3) & ~3;
        #pragma unroll 4
        for (int j = 0; j < jmax; j += 4) {
            int slot = j + grp;
            int src = __shfl(src_l, slot & 63, 64);
            if (slot < nloc) {
                uint4 v = x8[(size_t)src * 16 + fl];
                a0 += __uint_as_float(v.x << 16);
                a1 += __uint_as_float(v.x & 0xffff0000u);
                a2 += __uint_as_float(v.y << 16);
                a3 += __uint_as_float(v.y & 0xffff0000u);
                a4 += __uint_as_float(v.z << 16);
                a5 += __uint_as_float(v.z & 0xffff0000u);
                a6 += __uint_as_float(v.w << 16);
                a7 += __uint_as_float(v.w & 0xffff0000u);
            }
        }
    }
    a0 += __shfl_xor(a0, 16, 64); a0 += __shfl_xor(a0, 32, 64);
    a1 += __shfl_xor(a1, 16, 64); a1 += __shfl_xor(a1, 32, 64);
    a2 += __shfl_xor(a2, 16, 64); a2 += __shfl_xor(a2, 32, 64);
    a3 += __shfl_xor(a3, 16, 64); a3 += __shfl_xor(a3, 32, 64);
    a4 += __shfl_xor(a4, 16, 64); a4 += __shfl_xor(a4, 32, 64);
    a5 += __shfl_xor(a5, 16, 64); a5 += __shfl_xor(a5, 32, 64);
    a6 += __shfl_xor(a6, 16, 64); a6 += __shfl_xor(a6, 32, 64);
    a7 += __shfl_xor(a7, 16, 64); a7 += __shfl_xor(a7, 32, 64);
    if (grp == 0) {
        float inv = (e > s) ? 1.0f / (float)(e - s) : 0.0f;   // deg==0 -> agg = 0
        float v[8] = {a0*inv,a1*inv,a2*inv,a3*inv,a4*inv,a5*inv,a6*inv,a7*inv};
        uint_t h[8], l[8];
        #pragma unroll
        for (int k = 0; k < 8; k++) bf_split(v[k], h[k], l[k]);
        uint4 ho, lo;
        ho.x = h[0] | (h[1] << 16); ho.y = h[2] | (h[3] << 16);
        ho.z = h[4] | (h[5] << 16); ho.w = h[6] | (h[7] << 16);
        lo.x = l[0] | (l[1] << 16); lo.y = l[2] | (l[3] << 16);
        lo.z = l[4] | (l[5] << 16); lo.w = l[6] | (l[7] << 16);
        ((uint4*)agg_hi)[(size_t)node * 16 + fl] = ho;
        ((uint4*)agg_lo)[(size_t)node * 16 + fl] = lo;
    }
}

// ---------------------------------------------------------------------------
// MFMA GEMM: xout = relu(agg @ Wl^T + x @ Wr^T + b)
// A-side split-bf16 (hi+lo), weights bf16-hi only (4 MFMA terms/tile).
// Block 256 = 4 waves x 16 rows = 64 rows/block; LDS ~64KB -> 2 blocks/CU.
// Last layer (pool_out != null): fused mean-pool + FC with HIERARCHICAL
// reduction — 16-lane shfl per row-dot, LDS stash of 64 row-dots, wave 0
// segments by (sorted) graph id -> ~1-3 atomics per BLOCK instead of 64.
// (r11's 50K atomics into 16 cache lines serialized at the coherence point.)
// ---------------------------------------------------------------------------
__global__ __launch_bounds__(256, 2) void sage_gemm_mfma(
        const ushort_t* __restrict__ agg_hi, const ushort_t* __restrict__ agg_lo,
        const ushort_t* __restrict__ x_hi,   const ushort_t* __restrict__ x_lo,
        const ushort_t* __restrict__ wl_hi,  const ushort_t* __restrict__ wr_hi,
        const float* __restrict__ bias,
        ushort_t* __restrict__ out_hi, ushort_t* __restrict__ out_lo,
        const int* __restrict__ batch, const int* __restrict__ gstart,
        const float* __restrict__ fc_w, float* __restrict__ pool_out, int nrows) {
    __shared__ ushort_t whi_s[2][16384];    // 64 KB: [0]=Wl_hi, [1]=Wr_hi (swizzled)
    __shared__ float pool_red[64];
    int t = threadIdx.x;
    for (int i = t; i < 4096; i += 256) {   // 2 arrays x 128 rows x 16 chunks
        int a = i >> 11, rem = i & 2047, row = rem >> 4, ch = rem & 15;
        int sw = ch ^ (row & 7);
        const ushort_t* srcp = a ? wr_hi : wl_hi;
        uint4 v = *(const uint4*)(srcp + row * DIM + ch * 8);
        *(uint4*)((char*)&whi_s[a][0] + row * 256 + sw * 16) = v;
    }
    __syncthreads();

    int wave = t >> 6, lane = t & 63;
    int ml = lane & 15, quad = lane >> 4;
    int m0 = blockIdx.x * 64 + wave * 16;
    int row = m0 + ml;
    int rowc = (row < nrows) ? row : (nrows - 1);
    size_t abase = (size_t)rowc * DIM + quad * 8;

    f32x4 acc[8];
    #pragma unroll
    for (int i = 0; i < 8; i++) acc[i] = (f32x4)0.f;

    #pragma unroll
    for (int kc = 0; kc < DIM; kc += 32) {
        bf16x8 Aah = *(const bf16x8*)(agg_hi + abase + kc);
        bf16x8 Aal = *(const bf16x8*)(agg_lo + abase + kc);
        bf16x8 Axh = *(const bf16x8*)(x_hi   + abase + kc);
        bf16x8 Axl = *(const bf16x8*)(x_lo   + abase + kc);
        int kch = (kc >> 3) + quad;          // 16B-chunk index within row
        int sw16 = (kch ^ (ml & 7)) * 16;    // nrow&7 == ml&7 (n0*16 ≡ 0 mod 8)
        #pragma unroll
        for (int n0 = 0; n0 < 8; n0++) {
            int nrow = n0 * 16 + ml;
            bf16x8 b_lh = *(const bf16x8*)((const char*)&whi_s[0][0] + nrow * 256 + sw16);
            bf16x8 b_rh = *(const bf16x8*)((const char*)&whi_s[1][0] + nrow * 256 + sw16);
            f32x4 c = acc[n0];
            c = __builtin_amdgcn_mfma_f32_16x16x32_bf16(Aah, b_lh, c, 0, 0, 0);
            c = __builtin_amdgcn_mfma_f32_16x16x32_bf16(Aal, b_lh, c, 0, 0, 0);
            c = __builtin_amdgcn_mfma_f32_16x16x32_bf16(Axh, b_rh, c, 0, 0, 0);
            c = __builtin_amdgcn_mfma_f32_16x16x32_bf16(Axl, b_rh, c, 0, 0, 0);
            acc[n0] = c;
        }
    }

    if (pool_out) {
        // fused mean-pool + FC: per-row dot(relu(acc+bias), fc_w)
        float rd[4] = {0.f, 0.f, 0.f, 0.f};
        #pragma unroll
        for (int n0 = 0; n0 < 8; n0++) {
            int col = n0 * 16 + ml;
            float bv = bias[col];
            float w  = fc_w[col];
            #pragma unroll
            for (int r = 0; r < 4; r++)
                rd[r] += fmaxf(acc[n0][r] + bv, 0.f) * w;
        }
        #pragma unroll
        for (int r = 0; r < 4; r++) {
            #pragma unroll
            for (int off = 1; off < 16; off <<= 1)
                rd[r] += __shfl_xor(rd[r], off, 64);
        }
        if (ml == 0) {
            #pragma unroll
            for (int r = 0; r < 4; r++)
                pool_red[wave * 16 + quad * 4 + r] = rd[r];
        }
        __syncthreads();
        if (wave == 0) {
            int grow = blockIdx.x * 64 + lane;
            int valid = grow < nrows;
            int g = valid ? batch[grow] : 0;
            float v = 0.f;
            if (valid) v = pool_red[lane] / (float)(gstart[g + 1] - gstart[g]);
            int lastrow = blockIdx.x * 64 + 63;
            if (lastrow > nrows - 1) lastrow = nrows - 1;
            int g0 = batch[blockIdx.x * 64];
            int g1 = batch[lastrow];
            for (int gg = g0; gg <= g1; gg++) {       // <= ~3 iterations
                float part = (valid && g == gg) ? v : 0.f;
                #pragma unroll
                for (int off = 1; off < 64; off <<= 1)
                    part += __shfl_xor(part, off, 64);
                if (lane == 0) atomicAdd(&pool_out[gg], part);
            }
        }
    } else {
        #pragma unroll
        for (int n0 = 0; n0 < 8; n0++) {
            int col = n0 * 16 + ml;
            float bv = bias[col];
            #pragma unroll
            for (int r = 0; r < 4; r++) {
                int orow = m0 + quad * 4 + r;
                if (orow < nrows) {
                    float v = fmaxf(acc[n0][r] + bv, 0.f);
                    uint_t h, l;
                    bf_split(v, h, l);
                    out_hi[(size_t)orow * DIM + col] = (ushort_t)h;
                    out_lo[(size_t)orow * DIM + col] = (ushort_t)l;
                }
            }
        }
    }
}

// ---------------------------------------------------------------------------
extern "C" void kernel_launch(void* const* d_in, const int* in_sizes, int n_in,
                              void* d_out, int out_size, void* d_ws, size_t ws_size,
                              hipStream_t stream) {
    const float* x     = (const float*)d_in[0];
    const int*   ei    = (const int*)d_in[1];
    const int*   batch = (const int*)d_in[2];
    const float* Wl[3] = {(const float*)d_in[3], (const float*)d_in[6], (const float*)d_in[9]};
    const float* bb[3] = {(const float*)d_in[4], (const float*)d_in[7], (const float*)d_in[10]};
    const float* Wr[3] = {(const float*)d_in[5], (const float*)d_in[8], (const float*)d_in[11]};
    const float* fc_w  = (const float*)d_in[12];
    const float* fc_b  = (const float*)d_in[13];
    float* out = (float*)d_out;

    char* p = (char*)d_ws;
    auto alloc = [&](size_t bytes) { char* r = p; p += (bytes + 255) & ~255ull; return r; };
    int* bh        = (int*)alloc((size_t)BH_N * 4);
    int* bhofs     = (int*)alloc((size_t)(BH_N + 1) * 4);
    int* bsum      = (int*)alloc((size_t)BH_BLK * 4);
    uint_t* ebuf1  = (uint_t*)alloc((size_t)N_EDGES * 4);
    int* ebuf      = (int*)alloc((size_t)N_EDGES * 4);
    int* row_start = (int*)alloc((size_t)(N_NODES + 1) * 4);
    int* gstart    = (int*)alloc((size_t)(N_GRAPHS + 1) * 4);
    const size_t FB = (size_t)N_NODES * DIM * 2;     // feature buffer bytes (bf16)
    ushort_t* agg_hi = (ushort_t*)alloc(FB);
    ushort_t* agg_lo = (ushort_t*)alloc(FB);
    ushort_t* fh[3]  = {(ushort_t*)alloc(FB), (ushort_t*)alloc(FB), (ushort_t*)alloc(FB)};
    ushort_t* fl_[3] = {(ushort_t*)alloc(FB), (ushort_t*)alloc(FB), (ushort_t*)alloc(FB)};
    ushort_t* whi    = (ushort_t*)alloc((size_t)6 * 16384 * 2);

    const int* src = ei;
    const int* dst = ei + N_EDGES;

    prep_kernel<<<B1 + XS_BLOCKS + WS_BLOCKS + GB_BLOCKS + OI_BLOCKS, 256, 0, stream>>>(
        dst, bh, x, fh[0], fl_[0], Wl[0], Wr[0], Wl[1], Wr[1], Wl[2], Wr[2],
        whi, batch, gstart, fc_b, out);
    block_reduce_n<<<BH_BLK, 256, 0, stream>>>(bh, bsum, BH_N);
    scan_finalize<<<BH_BLK, SCAN_BLOCK, 0, stream>>>(bh, bsum, bhofs, BH_N, BH_BLK);
    p1_scatter<<<B1, 256, 0, stream>>>(src, dst, bhofs, ebuf1);
    p2_sort<<<NB1, 256, 0, stream>>>(ebuf1, bhofs, row_start, ebuf);

    // buffers: layer0 in fh[0] -> out fh[1]; layer1 in fh[1] -> out fh[2];
    // layer2 output fused into pool (no feature store).
    int inb = 0;
    for (int l = 0; l < 3; l++) {
        int outb = (l == 0) ? 1 : 2;
        agg_kernel<<<(N_NODES + 3) / 4, 256, 0, stream>>>(fh[inb], row_start, ebuf, agg_hi, agg_lo);
        sage_gemm_mfma<<<(N_NODES + 63) / 64, 256, 0, stream>>>(
            agg_hi, agg_lo, fh[inb], fl_[inb],
            whi + (size_t)(2 * l) * 16384, whi + (size_t)(2 * l + 1) * 16384,
            bb[l], fh[outb], fl_[outb],
            batch, gstart, fc_w, (l == 2) ? out : (float*)nullptr, N_NODES);
        inb = outb;
    }
}